// Round 1
// baseline (578.079 us; speedup 1.0000x reference)
//
#include <hip/hip_runtime.h>
#include <hip/hip_bf16.h>
#include <math.h>

// LineRWKVBlock: y = (x + sigmoid(x@Wr) * scan(x@Wv)) ; y += y@Wc
// B=16, W=2048, D=1024, decay=0.99.
//
// Pipeline (all bf16 MFMA for GEMMs; threshold 0.16375 permits it):
//  1. prep_weights: Wv,Wr,Wc fp32 [K][N] -> bf16 [N][K] (transposed) in ws
//  2. gemm_vr:  v = x@Wv (bf16 out), r = sigmoid(x@Wr) (bf16 out), fused N=2048
//  3. scan_partial: per-(b,chunk,d) local decayed sums of v  (16 chunks x 128)
//  4. scan_chunk:   16-step chunk-level scan -> per-chunk input states + new_state
//  5. scan_apply:   y_tmp = x + r*s   (overwrites v buffer in place, bf16)
//  6. gemm_mix: y = y_tmp + y_tmp@Wc  (fp32 out to d_out)
//
// ws layout: WT 6 MiB | v/y_tmp 64 MiB | r 64 MiB | sl 1 MiB | s_in 1 MiB = 136 MiB

#define DIMK 1024
#define MROWS 32768           // B*W
#define NCHUNK 16
#define CHUNKL 128
#define DECAY_F 0.99f
#define OM_F 0.01f

typedef __attribute__((ext_vector_type(8))) short short8;   // 8 bf16 (4 VGPRs)
typedef __attribute__((ext_vector_type(4))) float floatx4;

using bf16 = __hip_bfloat16;
using bf162 = __hip_bfloat162;

// ---------------- kernel 1: weight transpose + bf16 cast ----------------
// WT rows 0..1023 = Wv^T, 1024..2047 = Wr^T, 2048..3071 = Wc^T ; WT[n][k]
__global__ void prep_weights(const float* __restrict__ Wv,
                             const float* __restrict__ Wr,
                             const float* __restrict__ Wc,
                             bf16* __restrict__ WT) {
  __shared__ float tile[32][33];
  const int bk = blockIdx.x * 32;   // k block
  const int bn = blockIdx.y * 32;   // global n block (0..3071)
  const float* src;
  int nbase = bn;
  if (bn < 1024)      { src = Wv; }
  else if (bn < 2048) { src = Wr; nbase = bn - 1024; }
  else                { src = Wc; nbase = bn - 2048; }
  const int tx = threadIdx.x;       // 32
  const int ty = threadIdx.y;       // 8
  #pragma unroll
  for (int i = ty; i < 32; i += 8)
    tile[i][tx] = src[(size_t)(bk + i) * 1024 + nbase + tx];  // tile[k][n]
  __syncthreads();
  #pragma unroll
  for (int i = ty; i < 32; i += 8)
    WT[(size_t)(bn + i) * 1024 + bk + tx] = __float2bfloat16(tile[tx][i]);
}

// ---------------- kernel 2: fused v/r GEMM ----------------
// X fp32 [M][K]; WT bf16 [2048][K]; ntile 0..7 -> v, 8..15 -> sigmoid -> r
__global__ __launch_bounds__(256, 2) void gemm_vr(const float* __restrict__ X,
                                                  const bf16* __restrict__ WT,
                                                  bf16* __restrict__ Vout,
                                                  bf16* __restrict__ Rout) {
  __shared__ bf16 As[128][72];   // [m][k], +8 pad -> 2-way conflicts only (free)
  __shared__ bf16 Bs[128][72];   // [n][k]
  const int t = threadIdx.x;
  const int ntile = blockIdx.x;          // 0..15
  const int m0 = blockIdx.y * 128;
  const int lane = t & 63;
  const int wave = t >> 6;
  const int wm = wave >> 1, wn = wave & 1;
  const int ln15 = lane & 15, qd = lane >> 4;

  const bf16* Bsrc = WT + (size_t)(ntile * 128) * 1024;

  floatx4 acc[4][4];
  #pragma unroll
  for (int i = 0; i < 4; ++i)
    #pragma unroll
    for (int j = 0; j < 4; ++j) acc[i][j] = (floatx4){0.f, 0.f, 0.f, 0.f};

  for (int k0 = 0; k0 < 1024; k0 += 64) {
    // stage A (fp32 -> bf16): 8 float4 per thread
    #pragma unroll
    for (int p = 0; p < 8; ++p) {
      const int f = t + p * 256;
      const int row = f >> 4;            // 16 float4 per 64-col row
      const int c4 = f & 15;
      const float4 val = *(const float4*)&X[(size_t)(m0 + row) * 1024 + k0 + c4 * 4];
      union { ushort4 u; bf16 h[4]; } pk;
      pk.h[0] = __float2bfloat16(val.x);
      pk.h[1] = __float2bfloat16(val.y);
      pk.h[2] = __float2bfloat16(val.z);
      pk.h[3] = __float2bfloat16(val.w);
      *(ushort4*)&As[row][c4 * 4] = pk.u;
    }
    // stage B (bf16 passthrough): 4 x 16B per thread
    #pragma unroll
    for (int p = 0; p < 4; ++p) {
      const int o = t + p * 256;
      const int row = o >> 3;            // 8 uint4 per 64-col row
      const int c8 = o & 7;
      const uint4 val = *(const uint4*)&Bsrc[(size_t)row * 1024 + k0 + c8 * 8];
      *(uint4*)&Bs[row][c8 * 8] = val;
    }
    __syncthreads();
    #pragma unroll
    for (int kk = 0; kk < 64; kk += 32) {
      short8 fa[4], fb[4];
      #pragma unroll
      for (int tm = 0; tm < 4; ++tm)
        fa[tm] = *(const short8*)&As[wm * 64 + tm * 16 + ln15][kk + qd * 8];
      #pragma unroll
      for (int tn = 0; tn < 4; ++tn)
        fb[tn] = *(const short8*)&Bs[wn * 64 + tn * 16 + ln15][kk + qd * 8];
      #pragma unroll
      for (int tm = 0; tm < 4; ++tm)
        #pragma unroll
        for (int tn = 0; tn < 4; ++tn)
          acc[tm][tn] = __builtin_amdgcn_mfma_f32_16x16x32_bf16(
              fa[tm], fb[tn], acc[tm][tn], 0, 0, 0);
    }
    __syncthreads();
  }

  const bool isr = (ntile >= 8);
  bf16* outp = isr ? Rout : Vout;
  const int nc0 = (ntile & 7) * 128;
  #pragma unroll
  for (int tm = 0; tm < 4; ++tm) {
    #pragma unroll
    for (int i = 0; i < 4; ++i) {
      const int m_g = m0 + wm * 64 + tm * 16 + qd * 4 + i;   // row = quad*4 + reg
      const size_t rowoff = (size_t)m_g * 1024 + nc0;
      #pragma unroll
      for (int tn = 0; tn < 4; ++tn) {
        float cv = acc[tm][tn][i];
        if (isr) cv = 1.0f / (1.0f + __expf(-cv));
        outp[rowoff + wn * 64 + tn * 16 + ln15] = __float2bfloat16(cv);
      }
    }
  }
}

// ---------------- kernel 3: chunk-local decayed sums ----------------
__global__ void scan_partial(const bf16* __restrict__ V, float* __restrict__ sl) {
  const int idx = blockIdx.x * 256 + threadIdx.x;   // 131072 = B*NCHUNK*(D/2)
  const int d2 = idx & 511;
  const int c = (idx >> 9) & 15;
  const int b = idx >> 13;
  const bf162* V2 = (const bf162*)V;
  const size_t base = (size_t)(b * 2048 + c * 128) * 512 + d2;
  float s0 = 0.f, s1 = 0.f;
  for (int w = 0; w < CHUNKL; ++w) {
    const bf162 v = V2[base + (size_t)w * 512];
    s0 = DECAY_F * s0 + OM_F * __bfloat162float(v.x);
    s1 = DECAY_F * s1 + OM_F * __bfloat162float(v.y);
  }
  const int o = (b * 16 + c) * 1024 + d2 * 2;
  sl[o] = s0;
  sl[o + 1] = s1;
}

// ---------------- kernel 4: chunk-level scan ----------------
__global__ void scan_chunk(const float* __restrict__ state,
                           const float* __restrict__ sl,
                           float* __restrict__ sin_,
                           float* __restrict__ state_out,
                           float decayL) {
  const int idx = blockIdx.x * 256 + threadIdx.x;   // 16384 = B*D
  const int d = idx & 1023;
  const int b = idx >> 10;
  float s = state[idx];
  #pragma unroll
  for (int c = 0; c < NCHUNK; ++c) {
    const int o = (b * 16 + c) * 1024 + d;
    sin_[o] = s;
    s = decayL * s + sl[o];
  }
  state_out[idx] = s;
}

// ---------------- kernel 5: apply scan, y_tmp = x + r*s (in place over V) --
__global__ void scan_apply(const float* __restrict__ X,
                           const bf16* __restrict__ R,
                           const float* __restrict__ sin_,
                           bf16* __restrict__ VY) {
  const int idx = blockIdx.x * 256 + threadIdx.x;   // 131072
  const int d2 = idx & 511;
  const int c = (idx >> 9) & 15;
  const int b = idx >> 13;
  const bf162* R2 = (const bf162*)R;
  bf162* VY2 = (bf162*)VY;
  const float2* X2 = (const float2*)X;
  const size_t base = (size_t)(b * 2048 + c * 128) * 512 + d2;
  const int so = (b * 16 + c) * 1024 + d2 * 2;
  float s0 = sin_[so], s1 = sin_[so + 1];
  for (int w = 0; w < CHUNKL; ++w) {
    const size_t off = base + (size_t)w * 512;
    const bf162 v = VY2[off];
    const bf162 r = R2[off];
    const float2 xx = X2[off];
    s0 = DECAY_F * s0 + OM_F * __bfloat162float(v.x);
    s1 = DECAY_F * s1 + OM_F * __bfloat162float(v.y);
    const float y0 = xx.x + __bfloat162float(r.x) * s0;
    const float y1 = xx.y + __bfloat162float(r.y) * s1;
    bf162 o;
    o.x = __float2bfloat16(y0);
    o.y = __float2bfloat16(y1);
    VY2[off] = o;
  }
}

// ---------------- kernel 6: y = y_tmp + y_tmp @ Wc ----------------
__global__ __launch_bounds__(256, 2) void gemm_mix(const bf16* __restrict__ Yt,
                                                   const bf16* __restrict__ WcT,
                                                   float* __restrict__ Out) {
  __shared__ bf16 As[128][72];
  __shared__ bf16 Bs[128][72];
  const int t = threadIdx.x;
  const int nc0 = blockIdx.x * 128;      // 8 ntiles
  const int m0 = blockIdx.y * 128;
  const int lane = t & 63;
  const int wave = t >> 6;
  const int wm = wave >> 1, wn = wave & 1;
  const int ln15 = lane & 15, qd = lane >> 4;

  const bf16* Bsrc = WcT + (size_t)nc0 * 1024;

  floatx4 acc[4][4];
  #pragma unroll
  for (int i = 0; i < 4; ++i)
    #pragma unroll
    for (int j = 0; j < 4; ++j) acc[i][j] = (floatx4){0.f, 0.f, 0.f, 0.f};

  for (int k0 = 0; k0 < 1024; k0 += 64) {
    #pragma unroll
    for (int p = 0; p < 4; ++p) {        // A: bf16, 4 x 16B per thread
      const int o = t + p * 256;
      const int row = o >> 3;
      const int c8 = o & 7;
      const uint4 val = *(const uint4*)&Yt[(size_t)(m0 + row) * 1024 + k0 + c8 * 8];
      *(uint4*)&As[row][c8 * 8] = val;
    }
    #pragma unroll
    for (int p = 0; p < 4; ++p) {        // B
      const int o = t + p * 256;
      const int row = o >> 3;
      const int c8 = o & 7;
      const uint4 val = *(const uint4*)&Bsrc[(size_t)row * 1024 + k0 + c8 * 8];
      *(uint4*)&Bs[row][c8 * 8] = val;
    }
    __syncthreads();
    #pragma unroll
    for (int kk = 0; kk < 64; kk += 32) {
      short8 fa[4], fb[4];
      #pragma unroll
      for (int tm = 0; tm < 4; ++tm)
        fa[tm] = *(const short8*)&As[wm * 64 + tm * 16 + ln15][kk + qd * 8];
      #pragma unroll
      for (int tn = 0; tn < 4; ++tn)
        fb[tn] = *(const short8*)&Bs[wn * 64 + tn * 16 + ln15][kk + qd * 8];
      #pragma unroll
      for (int tm = 0; tm < 4; ++tm)
        #pragma unroll
        for (int tn = 0; tn < 4; ++tn)
          acc[tm][tn] = __builtin_amdgcn_mfma_f32_16x16x32_bf16(
              fa[tm], fb[tn], acc[tm][tn], 0, 0, 0);
    }
    __syncthreads();
  }

  #pragma unroll
  for (int tm = 0; tm < 4; ++tm) {
    #pragma unroll
    for (int i = 0; i < 4; ++i) {
      const int m_g = m0 + wm * 64 + tm * 16 + qd * 4 + i;
      const size_t rowoff = (size_t)m_g * 1024 + nc0;
      #pragma unroll
      for (int tn = 0; tn < 4; ++tn) {
        const size_t o = rowoff + wn * 64 + tn * 16 + ln15;
        Out[o] = __bfloat162float(Yt[o]) + acc[tm][tn][i];
      }
    }
  }
}

extern "C" void kernel_launch(void* const* d_in, const int* in_sizes, int n_in,
                              void* d_out, int out_size, void* d_ws, size_t ws_size,
                              hipStream_t stream) {
  const float* x     = (const float*)d_in[0];
  const float* state = (const float*)d_in[1];
  const float* Wv    = (const float*)d_in[2];
  const float* Wr    = (const float*)d_in[3];
  const float* Wc    = (const float*)d_in[4];

  float* y_out = (float*)d_out;
  float* state_out = y_out + (size_t)MROWS * 1024;

  char* ws = (char*)d_ws;
  bf16* WT   = (bf16*)ws;                                    // 3072*1024 bf16 = 6 MiB
  bf16* Vbuf = (bf16*)(ws + ((size_t)6 << 20));              // 64 MiB (also y_tmp)
  bf16* Rbuf = (bf16*)(ws + ((size_t)70 << 20));             // 64 MiB
  float* sl  = (float*)(ws + ((size_t)134 << 20));           // 1 MiB
  float* sin_ = (float*)(ws + ((size_t)135 << 20));          // 1 MiB
  bf16* WcT = WT + (size_t)2048 * 1024;

  const float decayL = (float)pow(0.99, (double)CHUNKL);

  prep_weights<<<dim3(32, 96), dim3(32, 8), 0, stream>>>(Wv, Wr, Wc, WT);
  gemm_vr<<<dim3(16, 256), 256, 0, stream>>>(x, WT, Vbuf, Rbuf);
  scan_partial<<<512, 256, 0, stream>>>(Vbuf, sl);
  scan_chunk<<<64, 256, 0, stream>>>(state, sl, sin_, state_out, decayL);
  scan_apply<<<512, 256, 0, stream>>>(x, Rbuf, sin_, Vbuf);
  gemm_mix<<<dim3(8, 256), 256, 0, stream>>>(Vbuf, WcT, y_out);
}

// Round 2
// 529.397 us; speedup vs baseline: 1.0920x; 1.0920x over previous
//
#include <hip/hip_runtime.h>
#include <hip/hip_bf16.h>
#include <math.h>

// LineRWKVBlock: y = (x + sigmoid(x@Wr) * scan(x@Wv)) ; y += y@Wc
// B=16, W=2048, D=1024, decay=0.99.
//
// R2 structure (m97-ladder step 3):
//  1. prep_x:       X fp32 -> bf16 Xb (one pass; A operand halves, no per-tile cvt)
//  2. prep_weights: Wv,Wr,Wc fp32 [K][N] -> bf16 [N][K] in ws
//  3. gemm_vr:      v = Xb@Wv, r = sigmoid(Xb@Wr); global_load_lds(16B) staging,
//                   BK=32 unpadded LDS tiles (2-way bank alias only), XCD swizzle
//  4. scan_partial: per-(b,chunk,d) local decayed sums of v
//  5. scan_chunk:   16-step chunk scan -> per-chunk input states + new_state
//  6. scan_apply:   y_tmp = xb + r*s (in place over V, bf16)
//  7. gemm_mix:     y = y_tmp + y_tmp@Wc (fp32 to d_out)
//
// ws: WT 6 MiB | Xb 64 | V/y_tmp 64 | R 64 | sl 1 | s_in 1  = 200 MiB

#define MROWS 32768           // B*W
#define NCHUNK 16
#define CHUNKL 128
#define DECAY_F 0.99f
#define OM_F 0.01f

typedef __attribute__((ext_vector_type(8))) short short8;   // 8 bf16 (4 VGPRs)
typedef __attribute__((ext_vector_type(4))) float floatx4;

using bf16 = __hip_bfloat16;
using bf162 = __hip_bfloat162;

// async global->LDS, 16B per lane; lds base must be wave-uniform, HW scatters
// lane i at base + i*16 (see cdna_hip_programming.md §5 caveat).
__device__ __forceinline__ void async_copy16(const bf16* g, bf16* l) {
  __builtin_amdgcn_global_load_lds(
      (const __attribute__((address_space(1))) unsigned int*)g,
      (__attribute__((address_space(3))) unsigned int*)l, 16, 0, 0);
}

// ---------------- kernel 1: x fp32 -> bf16 ----------------
__global__ void prep_x(const float* __restrict__ X, bf16* __restrict__ Xb) {
  const int idx = blockIdx.x * 256 + threadIdx.x;   // 8388608 float4-groups
  const float4 v = ((const float4*)X)[idx];
  union { ushort4 u; bf16 h[4]; } pk;
  pk.h[0] = __float2bfloat16(v.x);
  pk.h[1] = __float2bfloat16(v.y);
  pk.h[2] = __float2bfloat16(v.z);
  pk.h[3] = __float2bfloat16(v.w);
  ((ushort4*)Xb)[idx] = pk.u;
}

// ---------------- kernel 2: weight transpose + bf16 cast ----------------
// WT rows 0..1023 = Wv^T, 1024..2047 = Wr^T, 2048..3071 = Wc^T ; WT[n][k]
__global__ void prep_weights(const float* __restrict__ Wv,
                             const float* __restrict__ Wr,
                             const float* __restrict__ Wc,
                             bf16* __restrict__ WT) {
  __shared__ float tile[32][33];
  const int bk = blockIdx.x * 32;   // k block
  const int bn = blockIdx.y * 32;   // global n block (0..3071)
  const float* src;
  int nbase = bn;
  if (bn < 1024)      { src = Wv; }
  else if (bn < 2048) { src = Wr; nbase = bn - 1024; }
  else                { src = Wc; nbase = bn - 2048; }
  const int tx = threadIdx.x;       // 32
  const int ty = threadIdx.y;       // 8
  #pragma unroll
  for (int i = ty; i < 32; i += 8)
    tile[i][tx] = src[(size_t)(bk + i) * 1024 + nbase + tx];  // tile[k][n]
  __syncthreads();
  #pragma unroll
  for (int i = ty; i < 32; i += 8)
    WT[(size_t)(bn + i) * 1024 + bk + tx] = __float2bfloat16(tile[tx][i]);
}

// ---------------- kernel 3: fused v/r GEMM (global_load_lds, BK=32) --------
// Xb bf16 [M][K]; WT bf16 [2048][K]; nt 0..7 -> v, 8..15 -> sigmoid -> r
__global__ __launch_bounds__(256, 3) void gemm_vr(const bf16* __restrict__ Xb,
                                                  const bf16* __restrict__ WT,
                                                  bf16* __restrict__ Vout,
                                                  bf16* __restrict__ Rout) {
  __shared__ bf16 As[128][32];   // unpadded: global_load_lds needs contiguous;
  __shared__ bf16 Bs[128][32];   // BK=32 row=64B -> only 2-way bank alias (free)
  const int t = threadIdx.x;
  // XCD swizzle: id&7 -> mtile low bits so one XCD's blocks share the A tile
  const int id = blockIdx.x;                 // 4096 = 16 nt * 256 mt
  const int grp = id >> 3, xcd = id & 7;
  const int mt = ((grp >> 4) << 3) | xcd;    // NT=16
  const int nt = grp & 15;
  const int m0 = mt * 128;
  const int lane = t & 63, wave = t >> 6;
  const int wm = wave >> 1, wn = wave & 1;
  const int ln15 = lane & 15, qd = lane >> 4;

  const bf16* Asrc = Xb + (size_t)m0 * 1024;
  const bf16* Bsrc = WT + (size_t)(nt * 128) * 1024;

  // staging: wave covers 16 rows (64B each) per call; lane i -> row i/4, k-elems (i&3)*8
  const int srow = lane >> 2;
  const int skb  = (lane & 3) * 8;

  floatx4 acc[4][4];
  #pragma unroll
  for (int i = 0; i < 4; ++i)
    #pragma unroll
    for (int j = 0; j < 4; ++j) acc[i][j] = (floatx4){0.f, 0.f, 0.f, 0.f};

  for (int k0 = 0; k0 < 1024; k0 += 32) {
    #pragma unroll
    for (int s = 0; s < 2; ++s) {
      const int seg = wave * 2 + s;                 // 0..7
      const size_t roff = (size_t)(seg * 16 + srow) * 1024 + k0 + skb;
      async_copy16(&Asrc[roff], &As[seg * 16][0]);
      async_copy16(&Bsrc[roff], &Bs[seg * 16][0]);
    }
    __syncthreads();
    short8 fa[4], fb[4];
    #pragma unroll
    for (int tm = 0; tm < 4; ++tm)
      fa[tm] = *(const short8*)&As[wm * 64 + tm * 16 + ln15][qd * 8];
    #pragma unroll
    for (int tn = 0; tn < 4; ++tn)
      fb[tn] = *(const short8*)&Bs[wn * 64 + tn * 16 + ln15][qd * 8];
    #pragma unroll
    for (int tm = 0; tm < 4; ++tm)
      #pragma unroll
      for (int tn = 0; tn < 4; ++tn)
        acc[tm][tn] = __builtin_amdgcn_mfma_f32_16x16x32_bf16(
            fa[tm], fb[tn], acc[tm][tn], 0, 0, 0);
    __syncthreads();
  }

  const bool isr = (nt >= 8);
  bf16* outp = isr ? Rout : Vout;
  const int nc0 = (nt & 7) * 128;
  #pragma unroll
  for (int tm = 0; tm < 4; ++tm) {
    #pragma unroll
    for (int i = 0; i < 4; ++i) {
      const int m_g = m0 + wm * 64 + tm * 16 + qd * 4 + i;   // row = quad*4 + reg
      const size_t rowoff = (size_t)m_g * 1024 + nc0;
      #pragma unroll
      for (int tn = 0; tn < 4; ++tn) {
        float cv = acc[tm][tn][i];
        if (isr) cv = 1.0f / (1.0f + __expf(-cv));
        outp[rowoff + wn * 64 + tn * 16 + ln15] = __float2bfloat16(cv);
      }
    }
  }
}

// ---------------- kernel 4: chunk-local decayed sums ----------------
__global__ void scan_partial(const bf16* __restrict__ V, float* __restrict__ sl) {
  const int idx = blockIdx.x * 256 + threadIdx.x;   // 131072 = B*NCHUNK*(D/2)
  const int d2 = idx & 511;
  const int c = (idx >> 9) & 15;
  const int b = idx >> 13;
  const bf162* V2 = (const bf162*)V;
  const size_t base = (size_t)(b * 2048 + c * 128) * 512 + d2;
  float s0 = 0.f, s1 = 0.f;
  for (int w = 0; w < CHUNKL; ++w) {
    const bf162 v = V2[base + (size_t)w * 512];
    s0 = DECAY_F * s0 + OM_F * __bfloat162float(v.x);
    s1 = DECAY_F * s1 + OM_F * __bfloat162float(v.y);
  }
  const int o = (b * 16 + c) * 1024 + d2 * 2;
  sl[o] = s0;
  sl[o + 1] = s1;
}

// ---------------- kernel 5: chunk-level scan ----------------
__global__ void scan_chunk(const float* __restrict__ state,
                           const float* __restrict__ sl,
                           float* __restrict__ sin_,
                           float* __restrict__ state_out,
                           float decayL) {
  const int idx = blockIdx.x * 256 + threadIdx.x;   // 16384 = B*D
  const int d = idx & 1023;
  const int b = idx >> 10;
  float s = state[idx];
  #pragma unroll
  for (int c = 0; c < NCHUNK; ++c) {
    const int o = (b * 16 + c) * 1024 + d;
    sin_[o] = s;
    s = decayL * s + sl[o];
  }
  state_out[idx] = s;
}

// ---------------- kernel 6: y_tmp = xb + r*s (in place over V) ----------
__global__ void scan_apply(const bf16* __restrict__ Xb,
                           const bf16* __restrict__ R,
                           const float* __restrict__ sin_,
                           bf16* __restrict__ VY) {
  const int idx = blockIdx.x * 256 + threadIdx.x;   // 131072
  const int d2 = idx & 511;
  const int c = (idx >> 9) & 15;
  const int b = idx >> 13;
  const bf162* R2 = (const bf162*)R;
  const bf162* X2 = (const bf162*)Xb;
  bf162* VY2 = (bf162*)VY;
  const size_t base = (size_t)(b * 2048 + c * 128) * 512 + d2;
  const int so = (b * 16 + c) * 1024 + d2 * 2;
  float s0 = sin_[so], s1 = sin_[so + 1];
  for (int w = 0; w < CHUNKL; ++w) {
    const size_t off = base + (size_t)w * 512;
    const bf162 v = VY2[off];
    const bf162 r = R2[off];
    const bf162 xx = X2[off];
    s0 = DECAY_F * s0 + OM_F * __bfloat162float(v.x);
    s1 = DECAY_F * s1 + OM_F * __bfloat162float(v.y);
    const float y0 = __bfloat162float(xx.x) + __bfloat162float(r.x) * s0;
    const float y1 = __bfloat162float(xx.y) + __bfloat162float(r.y) * s1;
    bf162 o;
    o.x = __float2bfloat16(y0);
    o.y = __float2bfloat16(y1);
    VY2[off] = o;
  }
}

// ---------------- kernel 7: y = y_tmp + y_tmp @ Wc ----------------
__global__ __launch_bounds__(256, 3) void gemm_mix(const bf16* __restrict__ Yt,
                                                   const bf16* __restrict__ WcT,
                                                   float* __restrict__ Out) {
  __shared__ bf16 As[128][32];
  __shared__ bf16 Bs[128][32];
  const int t = threadIdx.x;
  const int id = blockIdx.x;                 // 2048 = 8 nt * 256 mt
  const int grp = id >> 3, xcd = id & 7;
  const int mt = ((grp >> 3) << 3) | xcd;    // NT=8
  const int nt = grp & 7;
  const int m0 = mt * 128;
  const int nc0 = nt * 128;
  const int lane = t & 63, wave = t >> 6;
  const int wm = wave >> 1, wn = wave & 1;
  const int ln15 = lane & 15, qd = lane >> 4;

  const bf16* Asrc = Yt + (size_t)m0 * 1024;
  const bf16* Bsrc = WcT + (size_t)nc0 * 1024;

  const int srow = lane >> 2;
  const int skb  = (lane & 3) * 8;

  floatx4 acc[4][4];
  #pragma unroll
  for (int i = 0; i < 4; ++i)
    #pragma unroll
    for (int j = 0; j < 4; ++j) acc[i][j] = (floatx4){0.f, 0.f, 0.f, 0.f};

  for (int k0 = 0; k0 < 1024; k0 += 32) {
    #pragma unroll
    for (int s = 0; s < 2; ++s) {
      const int seg = wave * 2 + s;
      const size_t roff = (size_t)(seg * 16 + srow) * 1024 + k0 + skb;
      async_copy16(&Asrc[roff], &As[seg * 16][0]);
      async_copy16(&Bsrc[roff], &Bs[seg * 16][0]);
    }
    __syncthreads();
    short8 fa[4], fb[4];
    #pragma unroll
    for (int tm = 0; tm < 4; ++tm)
      fa[tm] = *(const short8*)&As[wm * 64 + tm * 16 + ln15][qd * 8];
    #pragma unroll
    for (int tn = 0; tn < 4; ++tn)
      fb[tn] = *(const short8*)&Bs[wn * 64 + tn * 16 + ln15][qd * 8];
    #pragma unroll
    for (int tm = 0; tm < 4; ++tm)
      #pragma unroll
      for (int tn = 0; tn < 4; ++tn)
        acc[tm][tn] = __builtin_amdgcn_mfma_f32_16x16x32_bf16(
            fa[tm], fb[tn], acc[tm][tn], 0, 0, 0);
    __syncthreads();
  }

  #pragma unroll
  for (int tm = 0; tm < 4; ++tm) {
    #pragma unroll
    for (int i = 0; i < 4; ++i) {
      const int m_g = m0 + wm * 64 + tm * 16 + qd * 4 + i;
      const size_t rowoff = (size_t)m_g * 1024 + nc0;
      #pragma unroll
      for (int tn = 0; tn < 4; ++tn) {
        const size_t o = rowoff + wn * 64 + tn * 16 + ln15;
        Out[o] = __bfloat162float(Yt[o]) + acc[tm][tn][i];
      }
    }
  }
}

extern "C" void kernel_launch(void* const* d_in, const int* in_sizes, int n_in,
                              void* d_out, int out_size, void* d_ws, size_t ws_size,
                              hipStream_t stream) {
  const float* x     = (const float*)d_in[0];
  const float* state = (const float*)d_in[1];
  const float* Wv    = (const float*)d_in[2];
  const float* Wr    = (const float*)d_in[3];
  const float* Wc    = (const float*)d_in[4];

  float* y_out = (float*)d_out;
  float* state_out = y_out + (size_t)MROWS * 1024;

  char* ws = (char*)d_ws;
  bf16* WT   = (bf16*)ws;                                    // 6 MiB
  bf16* Xb   = (bf16*)(ws + ((size_t)6 << 20));              // 64 MiB
  bf16* Vbuf = (bf16*)(ws + ((size_t)70 << 20));             // 64 MiB (also y_tmp)
  bf16* Rbuf = (bf16*)(ws + ((size_t)134 << 20));            // 64 MiB
  float* sl  = (float*)(ws + ((size_t)198 << 20));           // 1 MiB
  float* sin_ = (float*)(ws + ((size_t)199 << 20));          // 1 MiB
  bf16* WcT = WT + (size_t)2048 * 1024;

  const float decayL = (float)pow(0.99, (double)CHUNKL);

  prep_x<<<32768, 256, 0, stream>>>(x, Xb);
  prep_weights<<<dim3(32, 96), dim3(32, 8), 0, stream>>>(Wv, Wr, Wc, WT);
  gemm_vr<<<4096, 256, 0, stream>>>(Xb, WT, Vbuf, Rbuf);
  scan_partial<<<512, 256, 0, stream>>>(Vbuf, sl);
  scan_chunk<<<64, 256, 0, stream>>>(state, sl, sin_, state_out, decayL);
  scan_apply<<<512, 256, 0, stream>>>(Xb, Rbuf, sin_, Vbuf);
  gemm_mix<<<2048, 256, 0, stream>>>(Vbuf, WcT, y_out);
}